// Round 1
// baseline (3450.733 us; speedup 1.0000x reference)
//
#include <hip/hip_runtime.h>
#include <hip/hip_bf16.h>

// ---------------- problem constants ----------------
#define NU      50000          // users
#define NT      100000         // total nodes
#define NPADR   100032         // NT padded to 64-row multiple
#define NC      5              // criteria
#define DD      64             // embedding dim
#define AA      32             // attention dim
#define EE      1600000        // edges per criterion
#define CE      (NC*EE)        // 8,000,000
#define CN      (NC*NT)        // 500,000
#define ROWF    (NC*DD)        // 320 floats per node row
#define NBL     1563           // ceil(NT/64)
#define NB4     25000          // NT/4

// ---------------- workspace layout (bytes) ----------------
// tmp/emb:   [0, 128,040,960)   (NPADR rows x 320 f32)  -- cursor aliases [0,2MB), bsum aliases [4MB,+4KB)
// edgebuf:   [128,040,960, 192,040,960)  8M x uint2
// offsets:   [192,040,960, +2,000,004)   CN+1 u32
// s2:        [194,041,088, +10,003,200)  25 x NPADR f32 -- counts (2MB) alias this (dead before s2 written)
// cri1:      [204,044,288, +1280)
// Wc:        [204,045,568, +163,840)     2 x 5 x 64 x 64 f32
#define TMP_OFF   0
#define EB_OFF    128040960
#define OFF_OFF   192040960
#define S2_OFF    194041088
#define CRI1_OFF  204044288
#define WC_OFF    204045568

__device__ __forceinline__ float lk(float x){ return x >= 0.f ? x : 0.3f*x; }
__device__ __forceinline__ float fast_tanh(float x){
  float e = __expf(2.0f*x);
  return (e - 1.0f) * __builtin_amdgcn_rcpf(e + 1.0f);
}

// ---------- CSR build: histogram ----------
__global__ __launch_bounds__(256) void dmcr_count(const int* __restrict__ rows,
                                                  unsigned* __restrict__ counts){
  const int c = blockIdx.y;
  const int t = blockIdx.x*256 + threadIdx.x;           // E divisible by 256
  const int r = rows[(size_t)c*EE + t];
  atomicAdd(&counts[c*NT + r], 1u);
}

// ---------- CSR build: 3-kernel exclusive scan over CN counters ----------
#define SCAN_NB 977   // ceil(CN/512)
__global__ __launch_bounds__(512) void dmcr_scan1(const unsigned* __restrict__ counts,
                                                  unsigned* __restrict__ offs,
                                                  unsigned* __restrict__ bsum){
  __shared__ unsigned sh[512];
  const int t = threadIdx.x; const int idx = blockIdx.x*512 + t;
  unsigned v = (idx < CN) ? counts[idx] : 0u;
  sh[t] = v; __syncthreads();
  for (int off=1; off<512; off<<=1){
    unsigned x = (t>=off) ? sh[t-off] : 0u; __syncthreads();
    sh[t] += x; __syncthreads();
  }
  if (idx < CN) offs[idx] = sh[t] - v;                  // block-local exclusive
  if (t == 511) bsum[blockIdx.x] = sh[511];
}
__global__ __launch_bounds__(1024) void dmcr_scan2(unsigned* __restrict__ bsum,
                                                   unsigned* __restrict__ offs){
  __shared__ unsigned sh[1024];
  const int t = threadIdx.x;
  unsigned v = (t < SCAN_NB) ? bsum[t] : 0u;
  sh[t] = v; __syncthreads();
  for (int off=1; off<1024; off<<=1){
    unsigned x = (t>=off) ? sh[t-off] : 0u; __syncthreads();
    sh[t] += x; __syncthreads();
  }
  if (t < SCAN_NB) bsum[t] = sh[t] - v;                 // exclusive block offsets
  if (t == 0) offs[CN] = (unsigned)CE;
}
__global__ __launch_bounds__(512) void dmcr_scan3(unsigned* __restrict__ offs,
                                                  const unsigned* __restrict__ bsum,
                                                  unsigned* __restrict__ cursor){
  const int idx = blockIdx.x*512 + threadIdx.x;
  if (idx < CN){ unsigned o = offs[idx] + bsum[blockIdx.x]; offs[idx] = o; cursor[idx] = o; }
}

// ---------- CSR build: scatter (col,val) packed ----------
__global__ __launch_bounds__(256) void dmcr_scatter(const int* __restrict__ rows,
                                                    const int* __restrict__ cols,
                                                    const float* __restrict__ vals,
                                                    unsigned* __restrict__ cursor,
                                                    uint2* __restrict__ eb){
  const int c = blockIdx.y;
  const size_t t = (size_t)blockIdx.x*256 + threadIdx.x;
  const size_t g = (size_t)c*EE + t;
  const int r = rows[g];
  unsigned slot = atomicAdd(&cursor[c*NT + r], 1u);
  eb[slot] = make_uint2((unsigned)cols[g], __float_as_uint(vals[g]));
}

// ---------- cri chain + cri_mean + zero item-pad row ----------
__global__ __launch_bounds__(320) void dmcr_cri(const float* __restrict__ cri0,
                                                const float* __restrict__ Wrel,
                                                float* __restrict__ cri1_ws,
                                                float* __restrict__ outp){
  __shared__ float s0[320], s1[320];
  const int t = threadIdx.x; const int c = t>>6, d = t&63;
  float v0 = cri0[t];
  s0[t] = v0; __syncthreads();
  float a = 0.f;
  #pragma unroll
  for (int k=0;k<DD;k++) a += s0[c*DD+k] * Wrel[k*DD + d];
  float v1 = lk(a); s1[t] = v1; cri1_ws[t] = v1; __syncthreads();
  float b = 0.f;
  #pragma unroll
  for (int k=0;k<DD;k++) b += s1[c*DD+k] * Wrel[DD*DD + k*DD + d];
  float v2 = lk(b);
  outp[32000320 + t] = (v0 + v1 + v2) * (1.f/3.f);      // cri_mean
  outp[32000000 + t] = 0.f;                             // items zero row
}

// ---------- combined Wc[l][c] = w_gcn * diag(cri_l[c]) * W_gc[l] ----------
__global__ __launch_bounds__(64) void dmcr_wc(const float* __restrict__ cri0,
                                              const float* __restrict__ cri1,
                                              const float* __restrict__ wgcn,
                                              const float* __restrict__ Wgc,
                                              float* __restrict__ Wc){
  const int b = blockIdx.x; const int l = b/5, c = b%5; const int j = threadIdx.x;
  const float* cri = (l==0 ? cri0 : cri1) + c*DD;
  float t[DD];
  #pragma unroll
  for (int d=0; d<DD; d++) t[d] = cri[d] * Wgc[l*DD*DD + d*DD + j];
  for (int i=0; i<DD; i++){
    float a = 0.f;
    #pragma unroll
    for (int d=0; d<DD; d++) a += wgcn[i*DD+d] * t[d];  // uniform -> s_load
    Wc[(size_t)((l*NC + c)*DD + i)*DD + j] = a;
  }
}

// ---------- gather-SpMM: tmp[r][c][d] = sum_e val*x[col][c][d] ----------
__global__ __launch_bounds__(256) void dmcr_spmm(const unsigned* __restrict__ offs,
                                                 const uint2* __restrict__ eb,
                                                 const float* __restrict__ xlo,
                                                 const float* __restrict__ xhi,
                                                 int split,
                                                 float* __restrict__ tmp){
  const int c = blockIdx.y;
  const int w = __builtin_amdgcn_readfirstlane(threadIdx.x >> 6);
  const int r = blockIdx.x*4 + w;                       // NT divisible by 4*NB4
  const int d = threadIdx.x & 63;
  const int oi = c*NT + r;
  unsigned beg = offs[oi], end = offs[oi+1];
  float acc = 0.f;
  unsigned e = beg;
  for (; e+1 < end; e += 2){
    uint2 cv0 = eb[e], cv1 = eb[e+1];
    const float* x0 = (cv0.x < (unsigned)split) ? xlo + (size_t)cv0.x*ROWF
                                                : xhi + (size_t)(cv0.x - split)*ROWF;
    const float* x1 = (cv1.x < (unsigned)split) ? xlo + (size_t)cv1.x*ROWF
                                                : xhi + (size_t)(cv1.x - split)*ROWF;
    acc += __uint_as_float(cv0.y) * x0[c*DD + d];
    acc += __uint_as_float(cv1.y) * x1[c*DD + d];
  }
  if (e < end){
    uint2 cv = eb[e];
    const float* x0 = (cv.x < (unsigned)split) ? xlo + (size_t)cv.x*ROWF
                                               : xhi + (size_t)(cv.x - split)*ROWF;
    acc += __uint_as_float(cv.y) * x0[c*DD + d];
  }
  tmp[(size_t)r*ROWF + c*DD + d] = acc;
}

// ---------- in-place emb = leaky(tmp @ Wc[c]) ; lanes = nodes, weights via s_load ----------
__global__ __launch_bounds__(64) void dmcr_emb(float* tmp_emb,
                                               const float* __restrict__ Wc,
                                               int layer){
  const int c = blockIdx.y;
  const int n = blockIdx.x*64 + threadIdx.x;            // <= NPADR, pad rows harmless
  float* row = tmp_emb + (size_t)n*ROWF + c*DD;
  const float* Wcc = Wc + (size_t)(layer*NC + c)*DD*DD;
  float acc[DD];
  #pragma unroll
  for (int d=0; d<DD; d++) acc[d] = 0.f;
  for (int k4=0; k4<DD/4; k4++){
    float4 t4 = *(const float4*)(row + k4*4);
    #pragma unroll
    for (int j=0; j<4; j++){
      float tk = (j==0)?t4.x:(j==1)?t4.y:(j==2)?t4.z:t4.w;
      const float* wr = Wcc + (k4*4+j)*DD;              // uniform -> s_load
      #pragma unroll
      for (int d=0; d<DD; d++) acc[d] += tk * wr[d];
    }
  }
  #pragma unroll
  for (int d4=0; d4<DD/4; d4++){
    float4 o;
    o.x = lk(acc[d4*4+0]); o.y = lk(acc[d4*4+1]);
    o.z = lk(acc[d4*4+2]); o.w = lk(acc[d4*4+3]);
    *(float4*)(row + d4*4) = o;                         // in-place: all reads done
  }
}

// ---------- s2[i][c][n] = sum_a tanh(emb[n,c,:]@W1[i,:,a]) * W2[i,a] ----------
__global__ __launch_bounds__(64) void dmcr_b1(const float* __restrict__ emb,
                                              const float* __restrict__ W1,
                                              const float* __restrict__ W2,
                                              float* __restrict__ s2){
  const int ic = blockIdx.y;                            // 0..24 : i = ic/5, c = ic%5 (uniform)
  const int i = ic/5, c = ic%5;
  const int n = blockIdx.x*64 + threadIdx.x;
  const float* er = emb + (size_t)n*ROWF + c*DD;
  const float* W1i = W1 + i*DD*AA;
  float acc[AA];
  #pragma unroll
  for (int a=0;a<AA;a++) acc[a] = 0.f;
  #pragma unroll 4
  for (int d4=0; d4<DD/4; d4++){
    float4 e4 = *(const float4*)(er + d4*4);
    #pragma unroll
    for (int j=0;j<4;j++){
      float e = (j==0)?e4.x:(j==1)?e4.y:(j==2)?e4.z:e4.w;
      const float* wr = W1i + (d4*4+j)*AA;              // uniform -> s_load
      #pragma unroll
      for (int a=0;a<AA;a++) acc[a] += e * wr[a];
    }
  }
  float sv = 0.f;
  const float* W2i = W2 + i*AA;
  #pragma unroll
  for (int a=0;a<AA;a++) sv += fast_tanh(acc[a]) * W2i[a];
  s2[(size_t)ic*NPADR + n] = sv;                        // coalesced
}

// ---------- softmax over c, pre = leaky(attn@emb), write/finalize out rows ----------
__global__ __launch_bounds__(320) void dmcr_b2(const float* __restrict__ emb,
                                               const float* __restrict__ s2,
                                               float* __restrict__ outp,
                                               const float* __restrict__ p0u,
                                               const float* __restrict__ p0i,
                                               int final){
  const int i = threadIdx.x >> 6;                       // wave = target criterion
  const int n = blockIdx.x*64 + (threadIdx.x & 63);
  if (n >= NT) return;
  float sv[NC];
  #pragma unroll
  for (int c=0;c<NC;c++) sv[c] = s2[(size_t)(i*NC+c)*NPADR + n];
  float m = sv[0];
  #pragma unroll
  for (int c=1;c<NC;c++) m = fmaxf(m, sv[c]);
  float at[NC]; float ssum = 0.f;
  #pragma unroll
  for (int c=0;c<NC;c++){ at[c] = __expf(sv[c]-m); ssum += at[c]; }
  float inv = __builtin_amdgcn_rcpf(ssum);
  #pragma unroll
  for (int c=0;c<NC;c++) at[c] *= inv;
  const float* er = emb + (size_t)n*ROWF;
  float* orow = outp + (size_t)n*ROWF + i*DD;
  const float* p0 = (n < NU ? p0u + (size_t)n*ROWF : p0i + (size_t)(n-NU)*ROWF) + i*DD;
  #pragma unroll 2
  for (int d4=0; d4<DD/4; d4++){
    float4 p = {0.f,0.f,0.f,0.f};
    #pragma unroll
    for (int c=0;c<NC;c++){
      float4 e4 = *(const float4*)(er + c*DD + d4*4);
      p.x += at[c]*e4.x; p.y += at[c]*e4.y; p.z += at[c]*e4.z; p.w += at[c]*e4.w;
    }
    p.x = lk(p.x); p.y = lk(p.y); p.z = lk(p.z); p.w = lk(p.w);
    if (final){
      float4 a0 = *(const float4*)(p0 + d4*4);          // pre0 (inputs)
      float4 b0 = *(const float4*)(orow + d4*4);        // pre1 (stored in out)
      p.x = (p.x + a0.x + b0.x)*(1.f/3.f); p.y = (p.y + a0.y + b0.y)*(1.f/3.f);
      p.z = (p.z + a0.z + b0.z)*(1.f/3.f); p.w = (p.w + a0.w + b0.w)*(1.f/3.f);
    }
    *(float4*)(orow + d4*4) = p;
  }
}

extern "C" void kernel_launch(void* const* d_in, const int* in_sizes, int n_in,
                              void* d_out, int out_size, void* d_ws, size_t ws_size,
                              hipStream_t stream) {
  const int*   rows = (const int*)  d_in[0];
  const int*   cols = (const int*)  d_in[1];
  const float* vals = (const float*)d_in[2];
  const float* ue   = (const float*)d_in[3];
  const float* ie   = (const float*)d_in[4];
  const float* cri0 = (const float*)d_in[5];
  const float* wgcn = (const float*)d_in[6];
  const float* Wgc  = (const float*)d_in[7];
  const float* Wrel = (const float*)d_in[8];
  const float* W1   = (const float*)d_in[9];
  const float* W2   = (const float*)d_in[10];
  float* outp = (float*)d_out;
  char*  ws   = (char*)d_ws;

  float*    tmp    = (float*)   (ws + TMP_OFF);
  uint2*    eb     = (uint2*)   (ws + EB_OFF);
  unsigned* offs   = (unsigned*)(ws + OFF_OFF);
  unsigned* counts = (unsigned*)(ws + S2_OFF);          // alias: dead before s2 written
  float*    s2     = (float*)   (ws + S2_OFF);
  float*    cri1   = (float*)   (ws + CRI1_OFF);
  float*    Wc     = (float*)   (ws + WC_OFF);
  unsigned* cursor = (unsigned*)(ws + 0);               // alias tmp[0,2MB)
  unsigned* bsum   = (unsigned*)(ws + 4*1024*1024);     // alias tmp[4MB,+4KB)

  // ---- build CSR (once, reused by both layers) ----
  hipMemsetAsync(counts, 0, CN*sizeof(unsigned), stream);
  dmcr_count  <<<dim3(EE/256, NC), 256, 0, stream>>>(rows, counts);
  dmcr_scan1  <<<SCAN_NB, 512, 0, stream>>>(counts, offs, bsum);
  dmcr_scan2  <<<1, 1024, 0, stream>>>(bsum, offs);
  dmcr_scan3  <<<SCAN_NB, 512, 0, stream>>>(offs, bsum, cursor);
  dmcr_scatter<<<dim3(EE/256, NC), 256, 0, stream>>>(rows, cols, vals, cursor, eb);

  // ---- tiny precomputes ----
  dmcr_cri<<<1, 320, 0, stream>>>(cri0, Wrel, cri1, outp);
  dmcr_wc <<<10, 64, 0, stream>>>(cri0, cri1, wgcn, Wgc, Wc);

  // ---- layer 1: x = concat(user_emb, item_emb) ; pre1 -> out rows ----
  dmcr_spmm<<<dim3(NB4, NC), 256, 0, stream>>>(offs, eb, ue, ie, NU, tmp);
  dmcr_emb <<<dim3(NBL, NC),  64, 0, stream>>>(tmp, Wc, 0);
  dmcr_b1  <<<dim3(NBL, 25),  64, 0, stream>>>(tmp, W1, W2, s2);
  dmcr_b2  <<<NBL, 320, 0, stream>>>(tmp, s2, outp, ue, ie, 0);

  // ---- layer 2: x = pre1 (out rows) ; out = (pre0+pre1+pre2)/3 ----
  dmcr_spmm<<<dim3(NB4, NC), 256, 0, stream>>>(offs, eb, outp, outp, NT, tmp);
  dmcr_emb <<<dim3(NBL, NC),  64, 0, stream>>>(tmp, Wc, 1);
  dmcr_b1  <<<dim3(NBL, 25),  64, 0, stream>>>(tmp, W1, W2, s2);
  dmcr_b2  <<<NBL, 320, 0, stream>>>(tmp, s2, outp, ue, ie, 1);
}

// Round 2
// 3044.626 us; speedup vs baseline: 1.1334x; 1.1334x over previous
//
#include <hip/hip_runtime.h>
#include <hip/hip_bf16.h>

// ---------------- problem constants ----------------
#define NU      50000
#define NT      100000
#define NPADR   100032         // 1563*64
#define NC      5
#define DD      64
#define AA      32
#define EE      1600000
#define CE      (NC*EE)        // 8,000,000
#define CN      (NC*NT)        // 500,000
#define ROWF    (NC*DD)        // 320
#define NBL     1563
#define OUT_ELEMS 32000000     // NT*ROWF

// ---------------- workspace layout (bytes) ----------------
#define TMP_OFF   0            // bf16 spmm out: NPADR*320*2 = 64,020,480
#define XB_OFF    64020480     // bf16 x rows:   64,020,480
#define EB_OFF    128040960    // packed edges:  32,000,000
#define OFF_OFF   160040960    // offs: (CN+1)*4
#define CNT_OFF   162040964    // counts: CN*4
#define RANK_OFF  164040964    // rank: CE*4 = 32,000,000
#define CRI1_OFF  196040964    // 1280
#define BSUM_OFF  196042244    // 977*4
#define WC_OFF    196046160    // 2*5*64*64*4 = 163,840  (16-aligned)

__device__ __forceinline__ float lk(float x){ return x >= 0.f ? x : 0.3f*x; }
__device__ __forceinline__ float fast_tanh(float x){
  float e = __expf(2.0f*x);
  return (e - 1.0f) * __builtin_amdgcn_rcpf(e + 1.0f);
}
__device__ __forceinline__ float bf2f(unsigned u){ return __uint_as_float(u << 16); }
__device__ __forceinline__ unsigned short f2bf_rn(float f){
  unsigned b = __float_as_uint(f);
  return (unsigned short)((b + 0x7FFFu + ((b >> 16) & 1u)) >> 16);
}

// ---------- input fp32 -> bf16 x rows ----------
__global__ __launch_bounds__(256) void dmcr_cvt(const float* __restrict__ ue,
                                                const float* __restrict__ ie,
                                                unsigned short* __restrict__ xb){
  size_t idx = ((size_t)blockIdx.x*256 + threadIdx.x) * 4;   // 31250 blocks, exact
  const float* src = (idx < (size_t)NU*ROWF) ? (ue + idx) : (ie + (idx - (size_t)NU*ROWF));
  float4 f = *(const float4*)src;
  ushort4 h;
  h.x = f2bf_rn(f.x); h.y = f2bf_rn(f.y); h.z = f2bf_rn(f.z); h.w = f2bf_rn(f.w);
  *(ushort4*)(xb + idx) = h;
}

// ---------- CSR build: histogram + per-edge rank ----------
__global__ __launch_bounds__(256) void dmcr_count(const int* __restrict__ rows,
                                                  unsigned* __restrict__ counts,
                                                  unsigned* __restrict__ rank){
  const int c = blockIdx.y;
  const size_t g = (size_t)c*EE + blockIdx.x*256 + threadIdx.x;
  const int r = rows[g];
  rank[g] = atomicAdd(&counts[c*NT + r], 1u);
}

// ---------- 3-kernel exclusive scan over CN counters ----------
#define SCAN_NB 977
__global__ __launch_bounds__(512) void dmcr_scan1(const unsigned* __restrict__ counts,
                                                  unsigned* __restrict__ offs,
                                                  unsigned* __restrict__ bsum){
  __shared__ unsigned sh[512];
  const int t = threadIdx.x; const int idx = blockIdx.x*512 + t;
  unsigned v = (idx < CN) ? counts[idx] : 0u;
  sh[t] = v; __syncthreads();
  for (int off=1; off<512; off<<=1){
    unsigned x = (t>=off) ? sh[t-off] : 0u; __syncthreads();
    sh[t] += x; __syncthreads();
  }
  if (idx < CN) offs[idx] = sh[t] - v;
  if (t == 511) bsum[blockIdx.x] = sh[511];
}
__global__ __launch_bounds__(1024) void dmcr_scan2(unsigned* __restrict__ bsum,
                                                   unsigned* __restrict__ offs){
  __shared__ unsigned sh[1024];
  const int t = threadIdx.x;
  unsigned v = (t < SCAN_NB) ? bsum[t] : 0u;
  sh[t] = v; __syncthreads();
  for (int off=1; off<1024; off<<=1){
    unsigned x = (t>=off) ? sh[t-off] : 0u; __syncthreads();
    sh[t] += x; __syncthreads();
  }
  if (t < SCAN_NB) bsum[t] = sh[t] - v;
  if (t == 0) offs[CN] = (unsigned)CE;
}
__global__ __launch_bounds__(512) void dmcr_scan3(unsigned* __restrict__ offs,
                                                  const unsigned* __restrict__ bsum){
  const int idx = blockIdx.x*512 + threadIdx.x;
  if (idx < CN) offs[idx] += bsum[blockIdx.x];
}

// ---------- scatter packed 4B edges: (col<<15)|q15, atomic-free ----------
__global__ __launch_bounds__(256) void dmcr_scatter(const int* __restrict__ rows,
                                                    const int* __restrict__ cols,
                                                    const float* __restrict__ vals,
                                                    const unsigned* __restrict__ offs,
                                                    const unsigned* __restrict__ rank,
                                                    unsigned* __restrict__ eb4){
  const int c = blockIdx.y;
  const size_t g = (size_t)c*EE + blockIdx.x*256 + threadIdx.x;
  const int r = rows[g];
  unsigned slot = offs[c*NT + r] + rank[g];
  unsigned q = (unsigned)(vals[g] * 3276700.0f + 0.5f);     // round(val/0.01*32767)
  q = q > 32767u ? 32767u : q;
  eb4[slot] = (((unsigned)cols[g]) << 15) | q;
}

// ---------- cri chain + cri_mean + zero item-pad row ----------
__global__ __launch_bounds__(320) void dmcr_cri(const float* __restrict__ cri0,
                                                const float* __restrict__ Wrel,
                                                float* __restrict__ cri1_ws,
                                                float* __restrict__ outp){
  __shared__ float s0[320], s1[320];
  const int t = threadIdx.x; const int c = t>>6, d = t&63;
  float v0 = cri0[t];
  s0[t] = v0; __syncthreads();
  float a = 0.f;
  #pragma unroll
  for (int k=0;k<DD;k++) a += s0[c*DD+k] * Wrel[k*DD + d];
  float v1 = lk(a); s1[t] = v1; cri1_ws[t] = v1; __syncthreads();
  float b = 0.f;
  #pragma unroll
  for (int k=0;k<DD;k++) b += s1[c*DD+k] * Wrel[DD*DD + k*DD + d];
  float v2 = lk(b);
  outp[OUT_ELEMS + 320 + t] = (v0 + v1 + v2) * (1.f/3.f);   // cri_mean
  outp[OUT_ELEMS + t] = 0.f;                                // items zero row
}

// ---------- Wc[l][c] = w_gcn * diag(cri_l[c]) * W_gc[l] ----------
__global__ __launch_bounds__(64) void dmcr_wc(const float* __restrict__ cri0,
                                              const float* __restrict__ cri1,
                                              const float* __restrict__ wgcn,
                                              const float* __restrict__ Wgc,
                                              float* __restrict__ Wc){
  const int b = blockIdx.x; const int l = b/5, c = b%5; const int j = threadIdx.x;
  const float* cri = (l==0 ? cri0 : cri1) + c*DD;
  float t[DD];
  #pragma unroll
  for (int d=0; d<DD; d++) t[d] = cri[d] * Wgc[l*DD*DD + d*DD + j];
  for (int i=0; i<DD; i++){
    float a = 0.f;
    #pragma unroll
    for (int d=0; d<DD; d++) a += wgcn[i*DD+d] * t[d];
    Wc[(size_t)((l*NC + c)*DD + i)*DD + j] = a;
  }
}

// ---------- gather-SpMM (bf16 x, bf16 out) ----------
__global__ __launch_bounds__(256) void dmcr_spmm(const unsigned* __restrict__ offs,
                                                 const unsigned* __restrict__ eb4,
                                                 const unsigned short* __restrict__ xb,
                                                 unsigned short* __restrict__ tmp16){
  const int c = blockIdx.y;
  const int w = __builtin_amdgcn_readfirstlane(threadIdx.x >> 6);
  const int r = blockIdx.x*4 + w;
  const int d = threadIdx.x & 63;
  const int oi = c*NT + r;
  const int co = c*DD + d;
  unsigned beg = offs[oi], end = offs[oi+1];
  float acc = 0.f;
  unsigned e = beg;
  for (; e+2 <= end; e += 2){
    unsigned p0 = eb4[e], p1 = eb4[e+1];
    float v0 = (float)(p0 & 0x7FFFu) * (0.01f/32767.f);
    float v1 = (float)(p1 & 0x7FFFu) * (0.01f/32767.f);
    float x0 = bf2f(xb[(size_t)(p0 >> 15)*ROWF + co]);
    float x1 = bf2f(xb[(size_t)(p1 >> 15)*ROWF + co]);
    acc = fmaf(v0, x0, acc);
    acc = fmaf(v1, x1, acc);
  }
  if (e < end){
    unsigned p0 = eb4[e];
    float v0 = (float)(p0 & 0x7FFFu) * (0.01f/32767.f);
    float x0 = bf2f(xb[(size_t)(p0 >> 15)*ROWF + co]);
    acc = fmaf(v0, x0, acc);
  }
  tmp16[(size_t)r*ROWF + co] = f2bf_rn(acc);
}

// ---------- fused layer: emb @ Wc -> leaky -> b1 -> softmax -> mix -> out ----------
// block = 320 threads (5 waves), tile = 64 nodes. LDS: bf16 tile (stride 322) + f32 sx.
#define SHS 322
__global__ __launch_bounds__(320) void dmcr_layer(const unsigned short* __restrict__ tmp16,
                                                  const float* __restrict__ Wc,
                                                  const float* __restrict__ W1,
                                                  const float* __restrict__ W2,
                                                  float* __restrict__ outp,
                                                  unsigned short* __restrict__ xb,
                                                  const float* __restrict__ ue,
                                                  const float* __restrict__ ie,
                                                  int layer){
  __shared__ unsigned short sh16[64*SHS];    // 41,216 B
  __shared__ float sx[1600];                 //  6,400 B  [i][c][n]
  const int t = threadIdx.x;
  const int w = __builtin_amdgcn_readfirstlane(t >> 6);   // wave = c (ph1-2), = i (ph3)
  const int lane = t & 63;
  const size_t base = (size_t)blockIdx.x * (64*ROWF);

  // ---- phase 0: coalesced stage of tile (raw bf16 copy) ----
  #pragma unroll
  for (int j = 0; j < 8; j++){
    int e = j*2560 + t*8;                    // 8 consecutive elems, within one row
    uint4 pk = *(const uint4*)(tmp16 + base + e);
    int n = e / ROWF, q = e % ROWF;
    unsigned* dst = (unsigned*)(sh16 + n*SHS + q);   // 4B aligned: SHS even, q mult of 8
    dst[0] = pk.x; dst[1] = pk.y; dst[2] = pk.z; dst[3] = pk.w;
  }
  __syncthreads();

  // ---- phase 1: emb[lane][c=w][:] = leaky( tmp_row @ Wc[layer][w] ) ----
  float acc[64];
  #pragma unroll
  for (int d = 0; d < 64; d++) acc[d] = 0.f;
  {
    const float* Wcc = Wc + ((size_t)(layer*NC + w))*DD*DD;
    const unsigned short* shr = sh16 + lane*SHS + w*DD;
    for (int k = 0; k < 64; k++){
      float tk = bf2f(shr[k]);
      const float* wr = Wcc + k*DD;          // wave-uniform -> s_load
      #pragma unroll
      for (int d = 0; d < 64; d++) acc[d] = fmaf(tk, wr[d], acc[d]);
    }
  }
  #pragma unroll
  for (int d = 0; d < 64; d++) acc[d] = lk(acc[d]);
  {  // write emb back (own row, own c-columns: no cross-lane hazard)
    unsigned short* shr = sh16 + lane*SHS + w*DD;
    #pragma unroll
    for (int d = 0; d < 64; d++) shr[d] = f2bf_rn(acc[d]);
  }

  // ---- phase 2: b1 — s[i] = sum_a tanh(emb @ W1[i]) * W2[i] ----
  #pragma unroll 1
  for (int i = 0; i < 5; i++){
    const float* W1i = W1 + i*DD*AA;
    float a2[AA];
    #pragma unroll
    for (int a = 0; a < AA; a++) a2[a] = 0.f;
    for (int k = 0; k < 64; k++){
      const float* wr = W1i + k*AA;          // uniform -> s_load
      float ev = acc[k];
      #pragma unroll
      for (int a = 0; a < AA; a++) a2[a] = fmaf(ev, wr[a], a2[a]);
    }
    float sv = 0.f;
    const float* W2i = W2 + i*AA;
    #pragma unroll
    for (int a = 0; a < AA; a++) sv += fast_tanh(a2[a]) * W2i[a];
    sx[i*320 + w*64 + lane] = sv;
  }
  __syncthreads();

  // ---- phase 3: softmax over c (for i=w) + mix pre = leaky(attn @ emb) ----
  {
    float sv[5];
    #pragma unroll
    for (int c = 0; c < 5; c++) sv[c] = sx[w*320 + c*64 + lane];
    float m = fmaxf(fmaxf(fmaxf(sv[0],sv[1]),fmaxf(sv[2],sv[3])),sv[4]);
    float at[5]; float ssum = 0.f;
    #pragma unroll
    for (int c = 0; c < 5; c++){ at[c] = __expf(sv[c]-m); ssum += at[c]; }
    float inv = __builtin_amdgcn_rcpf(ssum);
    #pragma unroll
    for (int d = 0; d < 64; d++) acc[d] = 0.f;  // reuse acc as pre
    #pragma unroll 1
    for (int c = 0; c < 5; c++){
      float a = at[c] * inv;
      const unsigned short* shr = sh16 + lane*SHS + c*DD;
      #pragma unroll
      for (int d = 0; d < 64; d++) acc[d] = fmaf(a, bf2f(shr[d]), acc[d]);
    }
    #pragma unroll
    for (int d = 0; d < 64; d++) acc[d] = lk(acc[d]);
  }
  __syncthreads();                            // everyone done reading emb
  {
    unsigned short* shr = sh16 + lane*SHS + w*DD;
    #pragma unroll
    for (int d = 0; d < 64; d++) shr[d] = f2bf_rn(acc[d]);
  }
  __syncthreads();

  // ---- phase 5: coalesced copy-out (+final combine) ----
  #pragma unroll
  for (int j = 0; j < 8; j++){
    int e = j*2560 + t*8;
    size_t gidx = base + e;
    if (gidx >= (size_t)OUT_ELEMS) continue;  // last tile guard (pad nodes)
    int n = e / ROWF, q = e % ROWF;
    const unsigned short* src = sh16 + n*SHS + q;
    float v[8];
    #pragma unroll
    for (int r = 0; r < 8; r++) v[r] = bf2f(src[r]);
    if (layer == 1){
      const float* p0 = (gidx < (size_t)NU*ROWF) ? (ue + gidx) : (ie + (gidx - (size_t)NU*ROWF));
      #pragma unroll
      for (int r = 0; r < 8; r += 4){
        float4 a0 = *(const float4*)(p0 + r);
        float4 o0 = *(const float4*)(outp + gidx + r);
        float4 ov;
        ov.x = (v[r+0] + a0.x + o0.x) * (1.f/3.f);
        ov.y = (v[r+1] + a0.y + o0.y) * (1.f/3.f);
        ov.z = (v[r+2] + a0.z + o0.z) * (1.f/3.f);
        ov.w = (v[r+3] + a0.w + o0.w) * (1.f/3.f);
        *(float4*)(outp + gidx + r) = ov;
      }
    } else {
      #pragma unroll
      for (int r = 0; r < 8; r += 4){
        float4 ov; ov.x = v[r+0]; ov.y = v[r+1]; ov.z = v[r+2]; ov.w = v[r+3];
        *(float4*)(outp + gidx + r) = ov;
      }
      ushort4 h0, h1;
      h0.x = f2bf_rn(v[0]); h0.y = f2bf_rn(v[1]); h0.z = f2bf_rn(v[2]); h0.w = f2bf_rn(v[3]);
      h1.x = f2bf_rn(v[4]); h1.y = f2bf_rn(v[5]); h1.z = f2bf_rn(v[6]); h1.w = f2bf_rn(v[7]);
      *(ushort4*)(xb + gidx) = h0;
      *(ushort4*)(xb + gidx + 4) = h1;
    }
  }
}

extern "C" void kernel_launch(void* const* d_in, const int* in_sizes, int n_in,
                              void* d_out, int out_size, void* d_ws, size_t ws_size,
                              hipStream_t stream) {
  const int*   rows = (const int*)  d_in[0];
  const int*   cols = (const int*)  d_in[1];
  const float* vals = (const float*)d_in[2];
  const float* ue   = (const float*)d_in[3];
  const float* ie   = (const float*)d_in[4];
  const float* cri0 = (const float*)d_in[5];
  const float* wgcn = (const float*)d_in[6];
  const float* Wgc  = (const float*)d_in[7];
  const float* Wrel = (const float*)d_in[8];
  const float* W1   = (const float*)d_in[9];
  const float* W2   = (const float*)d_in[10];
  float* outp = (float*)d_out;
  char*  ws   = (char*)d_ws;

  unsigned short* tmp16 = (unsigned short*)(ws + TMP_OFF);
  unsigned short* xb    = (unsigned short*)(ws + XB_OFF);
  unsigned*       eb4   = (unsigned*)      (ws + EB_OFF);
  unsigned*       offs  = (unsigned*)      (ws + OFF_OFF);
  unsigned*       counts= (unsigned*)      (ws + CNT_OFF);
  unsigned*       rank  = (unsigned*)      (ws + RANK_OFF);
  float*          cri1  = (float*)         (ws + CRI1_OFF);
  unsigned*       bsum  = (unsigned*)      (ws + BSUM_OFF);
  float*          Wc    = (float*)         (ws + WC_OFF);

  // CSR build (reused by both layers)
  hipMemsetAsync(counts, 0, CN*sizeof(unsigned), stream);
  dmcr_cvt    <<<31250, 256, 0, stream>>>(ue, ie, xb);
  dmcr_count  <<<dim3(EE/256, NC), 256, 0, stream>>>(rows, counts, rank);
  dmcr_scan1  <<<SCAN_NB, 512, 0, stream>>>(counts, offs, bsum);
  dmcr_scan2  <<<1, 1024, 0, stream>>>(bsum, offs);
  dmcr_scan3  <<<SCAN_NB, 512, 0, stream>>>(offs, bsum);
  dmcr_scatter<<<dim3(EE/256, NC), 256, 0, stream>>>(rows, cols, vals, offs, rank, eb4);

  // tiny precomputes
  dmcr_cri<<<1, 320, 0, stream>>>(cri0, Wrel, cri1, outp);
  dmcr_wc <<<10, 64, 0, stream>>>(cri0, cri1, wgcn, Wgc, Wc);

  // layer 1: x = bf16(concat(ue,ie)); writes pre1 -> outp (fp32) and xb (bf16)
  dmcr_spmm <<<dim3(NT/4, NC), 256, 0, stream>>>(offs, eb4, xb, tmp16);
  dmcr_layer<<<NBL, 320, 0, stream>>>(tmp16, Wc, W1, W2, outp, xb, ue, ie, 0);

  // layer 2: x = bf16(pre1); out = (pre0 + pre1 + pre2)/3
  dmcr_spmm <<<dim3(NT/4, NC), 256, 0, stream>>>(offs, eb4, xb, tmp16);
  dmcr_layer<<<NBL, 320, 0, stream>>>(tmp16, Wc, W1, W2, outp, xb, ue, ie, 1);
}